// Round 6
// baseline (255.691 us; speedup 1.0000x reference)
//
#include <hip/hip_runtime.h>

#define DIM    2048
#define SEQ    4096
#define BATCH  4
#define KW     4

typedef float fvec4 __attribute__((ext_vector_type(4)));  // native vector type

constexpr int  D4      = DIM / 4;                       // 512 fvec4 per row
constexpr long TOTAL4  = (long)BATCH * SEQ * D4;        // 8,388,608 fvec4
constexpr int  BLOCKSZ = 256;
constexpr int  NBLOCK  = 1024;                          // 4 blocks/CU persistent
constexpr int  NTHREAD = NBLOCK * BLOCKSZ;              // 262144
constexpr int  ITERS   = (int)(TOTAL4 / NTHREAD);       // 32 sweep steps

// Copy-clone address-order sweep. Evidence: six structurally different
// variants (burst / pinned / pipelined / long-stream) all froze at 81-85us
// while traffic varied 205-268MB and occupancy 17-51% -- the shared element
// is a SCATTERED instantaneous footprint (requests from all over the 537MB
// working set at once -> DRAM row thrash, ~40% efficiency). The two 6.3-6.7
// TB/s kernels in the same captures (fill, copy) both sweep a thin contiguous
// address slab. This kernel replicates that: grid-stride in linear address
// order, one fvec4 output per thread per iteration; the machine's in-flight
// frontier is a single ~4MB slab sweeping x/out. Halo rows x[t-1..t-3] lie
// 8-24KB behind the frontier -> L2/LLC-hot, so HBM reads each line ~once.
__global__ __launch_bounds__(BLOCKSZ) void ShortConv1D_78855599554935_kernel(
    const float* __restrict__ x, const float* __restrict__ w,
    const float* __restrict__ bias, float* __restrict__ out)
{
    int tid = blockIdx.x * BLOCKSZ + threadIdx.x;
    int d4  = tid & (D4 - 1);          // iteration-invariant (NTHREAD % 512 == 0)
    int row0 = tid >> 9;               // row index within [0, BATCH*SEQ)
    constexpr int ROWSTEP = NTHREAD >> 9;  // 512 rows per sweep step

    const fvec4* __restrict__ x4 = (const fvec4*)x;
    const fvec4* __restrict__ w4 = (const fvec4*)w;
    const fvec4* __restrict__ b4 = (const fvec4*)bias;
    fvec4* __restrict__ o4 = (fvec4*)out;

    // weight rows for channels d = 4*d4 + j  (w is [D,K] row-major, K=4)
    fvec4 w0 = w4[d4 * 4 + 0];
    fvec4 w1 = w4[d4 * 4 + 1];
    fvec4 w2 = w4[d4 * 4 + 2];
    fvec4 w3 = w4[d4 * 4 + 3];
    fvec4 bv = b4[d4];

#pragma unroll 2
    for (int it = 0; it < ITERS; ++it) {
        int  row = row0 + it * ROWSTEP;        // wave-uniform
        int  t   = row & (SEQ - 1);            // wave-uniform time index
        long g   = ((long)row << 9) | d4;      // linear fvec4 address

        // frontier load first (the only likely HBM miss), then trailing halo
        fvec4 dd = x4[g];
        fvec4 a, bq, c;
        if (t >= 3) {                          // wave-uniform fast path
            c  = x4[g - 1 * D4];
            bq = x4[g - 2 * D4];
            a  = x4[g - 3 * D4];
        } else {                               // 3 rows per batch only
            c  = (t >= 1) ? x4[g - 1 * D4] : (fvec4)(0.f);
            bq = (t >= 2) ? x4[g - 2 * D4] : (fvec4)(0.f);
            a  = (fvec4)(0.f);
        }

        fvec4 r;
        r.x = bv.x + w0.x * a.x + w0.y * bq.x + w0.z * c.x + w0.w * dd.x;
        r.y = bv.y + w1.x * a.y + w1.y * bq.y + w1.z * c.y + w1.w * dd.y;
        r.z = bv.z + w2.x * a.z + w2.y * bq.z + w2.z * c.z + w2.w * dd.z;
        r.w = bv.w + w3.x * a.w + w3.y * bq.w + w3.z * c.w + w3.w * dd.w;
        o4[g] = r;
    }
}

extern "C" void kernel_launch(void* const* d_in, const int* in_sizes, int n_in,
                              void* d_out, int out_size, void* d_ws, size_t ws_size,
                              hipStream_t stream) {
    const float* x = (const float*)d_in[0];
    const float* w = (const float*)d_in[1];
    const float* b = (const float*)d_in[2];
    float* out = (float*)d_out;

    ShortConv1D_78855599554935_kernel<<<NBLOCK, BLOCKSZ, 0, stream>>>(x, w, b, out);
}